// Round 8
// baseline (380.953 us; speedup 1.0000x reference)
//
#include <hip/hip_runtime.h>
#include <math.h>

typedef unsigned short u16;
typedef unsigned int   u32;
typedef unsigned int   u32x2 __attribute__((ext_vector_type(2)));
typedef float f32x4  __attribute__((ext_vector_type(4)));
typedef float f32x16 __attribute__((ext_vector_type(16)));
typedef __bf16 bf16x8 __attribute__((ext_vector_type(8)));
typedef __bf16 bf16x2 __attribute__((ext_vector_type(2)));

#define SEQ   2048
#define BATCH 4
#define NH    16
#define DK    64
#define DM    1024
#define MTOT  (SEQ*BATCH)   /* 8192 rows */
#define SCL_QK 0.18033688011116016f   /* log2(e)/sqrt(64), folded into Q proj */

#if __has_builtin(__builtin_amdgcn_exp2f)
#define EXP2(x) __builtin_amdgcn_exp2f(x)
#else
#define EXP2(x) exp2f(x)
#endif

// in-place half-wave swap: d0.hi <-> d1.lo  (v_permlane32_swap_b32)
#if __has_builtin(__builtin_amdgcn_permlane32_swap)
#define PLSWAP(X, Y) do {                                          \
    u32x2 _r = __builtin_amdgcn_permlane32_swap((X), (Y), false, false); \
    (X) = _r.x; (Y) = _r.y;                                        \
  } while (0)
#else
#define PLSWAP(X, Y) \
  asm("v_permlane32_swap_b32 %0, %1" : "+v"(X), "+v"(Y))
#endif

#define WAITCNT_VM(N) asm volatile("s_waitcnt vmcnt(" #N ")" ::: "memory")
#define BARRIER_FENCED() do {                                  \
    asm volatile("" ::: "memory");                             \
    __builtin_amdgcn_s_barrier();                              \
    asm volatile("" ::: "memory");                             \
  } while (0)

template<int N> static __device__ __forceinline__ void vm_wait() {
  if constexpr (N == 0)      asm volatile("s_waitcnt vmcnt(0)" ::: "memory");
  else if constexpr (N == 3) asm volatile("s_waitcnt vmcnt(3)" ::: "memory");
  else if constexpr (N == 4) asm volatile("s_waitcnt vmcnt(4)" ::: "memory");
  else static_assert(N == 0, "unsupported vmcnt");
}

static __device__ __forceinline__ u16 f2bf(float f) {
  __bf16 h = (__bf16)f;
  return __builtin_bit_cast(u16, h);
}
static __device__ __forceinline__ u32 pk2(float a, float b) {
  bf16x2 t = {(__bf16)a, (__bf16)b};          // -> v_cvt_pk_bf16_f32
  return __builtin_bit_cast(u32, t);
}

typedef __attribute__((address_space(1))) const void g1_t;
typedef __attribute__((address_space(3))) void l3_t;
static __device__ __forceinline__ void gload16(const void* g, void* l) {
  __builtin_amdgcn_global_load_lds((g1_t*)g, (l3_t*)l, 16, 0, 0);
}

static __device__ __forceinline__ void cast8(const float* __restrict__ src,
                                             u16* __restrict__ dst, int i) {
  float4 a = ((const float4*)src)[2 * i];
  float4 b = ((const float4*)src)[2 * i + 1];
  uint4 r;
  r.x = pk2(a.x, a.y); r.y = pk2(a.z, a.w);
  r.z = pk2(b.x, b.y); r.w = pk2(b.z, b.w);
  ((uint4*)dst)[i] = r;
}

// single-tensor cast (split path)
__global__ __launch_bounds__(256)
void cast_bf16(const float* __restrict__ src, u16* __restrict__ dst, int n8) {
  int i = blockIdx.x * 256 + threadIdx.x;
  if (i < n8) cast8(src, dst, i);
}

// weights-only fused cast: Wq,Wk,Wv -> w3 [3*DM,DM]; Wo -> wo_c. 2048 blocks.
__global__ __launch_bounds__(256)
void cast_w(const float* __restrict__ Wq, const float* __restrict__ Wk,
            const float* __restrict__ Wv, const float* __restrict__ Wo,
            u16* __restrict__ w3, u16* __restrict__ wo_c) {
  int bid = blockIdx.x;
  int t = bid >> 9, idx = bid & 511;
  const float* src = (t == 0) ? Wq : (t == 1) ? Wk : (t == 2) ? Wv : Wo;
  u16* dst = (t < 3) ? (w3 + (size_t)t * DM * DM) : wo_c;
  cast8(src, dst, idx * 256 + threadIdx.x);
}

// everything-cast: q,k,v (4096 blocks each) + 4 weights (512 each) = 14336 blocks.
__global__ __launch_bounds__(256)
void cast_all(const float* __restrict__ q, const float* __restrict__ k,
              const float* __restrict__ v,
              const float* __restrict__ Wq, const float* __restrict__ Wk,
              const float* __restrict__ Wv, const float* __restrict__ Wo,
              u16* __restrict__ in_c, u16* __restrict__ w3, u16* __restrict__ wo_c) {
  int bid = blockIdx.x;
  const float* src; u16* dst; int idx;
  if (bid < 12288) {
    int t = bid >> 12; idx = bid & 4095;
    src = (t == 0) ? q : (t == 1) ? k : v;
    dst = in_c + (size_t)t * MTOT * DM;
  } else {
    int wb = bid - 12288;
    int t = wb >> 9; idx = wb & 511;
    src = (t == 0) ? Wq : (t == 1) ? Wk : (t == 2) ? Wv : Wo;
    dst = (t < 3) ? (w3 + (size_t)t * DM * DM) : wo_c;
  }
  cast8(src, dst, idx * 256 + threadIdx.x);
}

// Projection GEMM — v8: BM=64 x BN=128 x BK=32 tile (24 KB LDS -> 6 blocks/CU,
// 24 waves/CU vs 16). Same 2-phase counted-vmcnt schedule and hazard proof as
// the verified R4 core; latency-bound regime fixed via block-TLP, not pipeline
// depth (R3/R4/R7 post-mortems). 4 waves in 1x4: each wave = 64 rows x 32 cols,
// acc[4][2] (32 acc regs, no spill). Stage = 1 A-gload + 2 B-gload -> vmcnt(3).
// OGEMM=0: seg = seg_base + bx>>3 picks {Q,K,V}: A in [SEQ,BATCH,DM] order, W = w3 seg,
//          epilogue: seg0 -> o0 [b,h,s,dk]*SCL_QK; seg1 -> o1 [b,h,s,dk]; seg2 -> o2 [b,h,dk,s]
// OGEMM=1: A = ctx row-major [M,DM], W = wo_c, out f32 o3 [(s*B+b)*DM+n]
template<int OGEMM>
__global__ __launch_bounds__(256, 4)
void gemm_k(const u16* __restrict__ a0, const u16* __restrict__ a1,
            const u16* __restrict__ a2, const u16* __restrict__ w3,
            const float* __restrict__ b0, const float* __restrict__ b1,
            const float* __restrict__ b2,
            u16* __restrict__ o0, u16* __restrict__ o1, u16* __restrict__ o2,
            float* __restrict__ o3, int seg_base)
{
  constexpr int BM = 64, BN = 128, BK = 32;
  __shared__ u16 As[2][BM * BK];   // 8 KB
  __shared__ u16 Bs[2][BN * BK];   // 16 KB

  // T1 chunked XCD swizzle (nwg = 3072 / 1024 / ... all %8 == 0 -> bijective)
  const int nwg = gridDim.x * gridDim.y;
  const int bid = blockIdx.y * gridDim.x + blockIdx.x;
  const int swz = (bid & 7) * (nwg >> 3) + (bid >> 3);
  const int bx  = swz % gridDim.x;
  const int by  = swz / gridDim.x;

  const int seg = OGEMM ? 0 : (seg_base + (int)(bx >> 3));
  const int n0  = OGEMM ? bx * BN : (bx & 7) * BN;
  const int m0  = by * BM;
  const u16* A = OGEMM ? a0 : (seg == 0 ? a0 : seg == 1 ? a1 : a2);
  const u16* W = OGEMM ? w3 : (w3 + (size_t)seg * DM * DM);
  const float* bias = OGEMM ? b0 : (seg == 0 ? b0 : seg == 1 ? b1 : b2);

  const int tid  = threadIdx.x;
  const int w    = tid >> 6;
  const int lane = tid & 63;
  const int quad = lane >> 4;
  const int l15  = lane & 15;
  const int wn   = w * 32;          // wave cols; wm = 0 (all waves span 64 rows)

  // staging addresses
  size_t aoff, woff[2];
  {
    int arow = w * 16 + (lane >> 2);          // 16 rows/wave, 4 lanes/row
    int gm = m0 + arow;
    if (OGEMM) {
      aoff = (size_t)gm * DM + (lane & 3) * 8;
    } else {
      int bb = gm >> 11, s = gm & (SEQ - 1);
      aoff = (size_t)(s * BATCH + bb) * DM + (lane & 3) * 8;
    }
    for (int p = 0; p < 2; p++) {
      int brow = w * 32 + p * 16 + (lane >> 2);
      woff[p] = (size_t)(n0 + brow) * DM + (lane & 3) * 8;
    }
  }

  f32x4 acc[4][2];
  for (int i = 0; i < 4; i++)
    for (int j = 0; j < 2; j++)
      acc[i][j] = (f32x4){0.f, 0.f, 0.f, 0.f};

  auto stage = [&](int kt, int bufi) {
    gload16(A + aoff + kt * BK, &As[bufi][w * 16 * BK]);
#pragma unroll
    for (int p = 0; p < 2; p++)
      gload16(W + woff[p] + kt * BK, &Bs[bufi][(w * 32 + p * 16) * BK]);
  };
  auto compute = [&](int cur) {
    bf16x8 af[4], bfr[2];
#pragma unroll
    for (int i = 0; i < 4; i++)
      af[i] = *(const bf16x8*)&As[cur][(i * 16 + l15) * BK + quad * 8];
#pragma unroll
    for (int j = 0; j < 2; j++)
      bfr[j] = *(const bf16x8*)&Bs[cur][(wn + j * 16 + l15) * BK + quad * 8];
#pragma unroll
    for (int i = 0; i < 4; i++)
#pragma unroll
      for (int j = 0; j < 2; j++)
        acc[i][j] = __builtin_amdgcn_mfma_f32_16x16x32_bf16(af[i], bfr[j], acc[i][j], 0, 0, 0);
  };

  constexpr int NKT = DM / BK;   // 32
  stage(0, 0);
  for (int kt = 0; kt < NKT - 1; kt++) {
    const int cur = kt & 1;
    stage(kt + 1, cur ^ 1);      // issue next tile first (3 loads)
    vm_wait<3>();                // tile kt retired; kt+1's 3 loads in flight
    BARRIER_FENCED();
    compute(cur);
    BARRIER_FENCED();            // readers done before next iter's stage overwrite
  }
  vm_wait<0>();                  // final tile: full drain
  BARRIER_FENCED();
  compute((NKT - 1) & 1);

  // C/D layout: col(n) = lane&15, row(m) = quad*4 + reg
  for (int j = 0; j < 2; j++) {
    int gn = n0 + wn + j * 16 + l15;
    float bv = bias[gn];
    int h = gn >> 6, dk = gn & 63;
    for (int i = 0; i < 4; i++) {
      int gmb = m0 + i * 16 + quad * 4;
      for (int r = 0; r < 4; r++) {
        int gm = gmb + r;
        float val = acc[i][j][r] + bv;
        int bb = gm >> 11, s = gm & (SEQ - 1);
        if (OGEMM) {
          o3[(size_t)(s * BATCH + bb) * DM + gn] = val;
        } else if (seg == 0) {
          o0[((size_t)(bb * NH + h) * SEQ + s) * DK + dk] = f2bf(val * SCL_QK);
        } else if (seg == 1) {
          o1[((size_t)(bb * NH + h) * SEQ + s) * DK + dk] = f2bf(val);
        } else {
          o2[((size_t)(bb * NH + h) * DK + dk) * SEQ + s] = f2bf(val);
        }
      }
    }
  }
}

// ---------------------------------------------------------------------------
// Flash attention (R7 core, kept): 32x32x16 MFMA, permlane32_swap P-exchange,
// 2-buffer depth-1 K/V pipeline with counted vmcnt.
__global__ __launch_bounds__(256, 4)
void attn3(const u16* __restrict__ Q, const u16* __restrict__ K,
           const u16* __restrict__ VT, u16* __restrict__ ctx)
{
  __shared__ u16 Ks[2][64 * 64];
  __shared__ u16 Vs[2][64 * 64];

  const int bh = blockIdx.x;
  const int qt = blockIdx.y;
  const int b  = bh >> 4, h = bh & 15;
  const int tid  = threadIdx.x;
  const int w    = tid >> 6;
  const int lane = tid & 63;
  const int l31  = lane & 31;
  const int hi   = lane >> 5;

  const u16* Qb = Q  + (size_t)bh * SEQ * DK;
  const u16* Kb = K  + (size_t)bh * SEQ * DK;
  const u16* Vb = VT + (size_t)bh * DK * SEQ;

  const int qbase = qt * 128 + w * 32;
  const int qrow  = qbase + l31;

  bf16x8 qf[4];
#pragma unroll
  for (int ks = 0; ks < 4; ks++)
    qf[ks] = *(const bf16x8*)&Qb[(size_t)qrow * DK + ks * 16 + hi * 8];

  const int r0 = tid >> 3;
  const int sw = (tid & 7) ^ (r0 & 7);

#define STAGE(kbb, bufi) do {                                                       \
    _Pragma("unroll")                                                               \
    for (int p = 0; p < 2; p++) {                                                   \
      int row = p * 32 + r0;                                                        \
      gload16(&Kb[(size_t)((kbb) * 64 + row) * DK + sw * 8],                        \
              &Ks[bufi][(p * 32 + w * 8) * 64]);                                    \
      gload16(&Vb[(size_t)row * SEQ + (kbb) * 64 + sw * 8],                         \
              &Vs[bufi][(p * 32 + w * 8) * 64]);                                    \
    }                                                                               \
  } while (0)

  f32x16 z16;
#pragma unroll
  for (int i = 0; i < 16; i++) z16[i] = 0.f;

  f32x16 ot0 = z16, ot1 = z16;
  float2 ls2 = {0.f, 0.f};

  u32 wp[8];

#define SOFTMAX_BLK(SA) do {                                                        \
    _Pragma("unroll")                                                               \
    for (int g = 0; g < 8; g++) {                                                   \
      float pa = EXP2(SA[2 * g]);                                                   \
      float pb = EXP2(SA[2 * g + 1]);                                               \
      ls2.x += pa; ls2.y += pb;                                                     \
      wp[g] = pk2(pa, pb);                                                          \
    }                                                                               \
  } while (0)

#define PVSTEP(VsB, KSB, KSL) do {                                                  \
    u32 a0 = wp[(KSB) * 4 + 0], a1 = wp[(KSB) * 4 + 1];                             \
    u32 a2 = wp[(KSB) * 4 + 2], a3 = wp[(KSB) * 4 + 3];                             \
    PLSWAP(a0, a2);                                                                 \
    PLSWAP(a1, a3);                                                                 \
    uint4 pw;                                                                       \
    pw.x = a0; pw.y = a1; pw.z = a2; pw.w = a3;                                     \
    bf16x8 pf = __builtin_bit_cast(bf16x8, pw);                                     \
    const int gg = (((KSL) * 2 + hi) ^ (l31 & 7)) * 8;                              \
    bf16x8 vf0 = *(const bf16x8*)&VsB[l31 * 64 + gg];                               \
    bf16x8 vf1 = *(const bf16x8*)&VsB[(32 + l31) * 64 + gg];                        \
    ot0 = __builtin_amdgcn_mfma_f32_32x32x16_bf16(vf0, pf, ot0, 0, 0, 0);           \
    ot1 = __builtin_amdgcn_mfma_f32_32x32x16_bf16(vf1, pf, ot1, 0, 0, 0);           \
  } while (0)

#define BODY(curi) do {                                                             \
    const u16* KsB = &Ks[curi][0];                                                  \
    const u16* VsB = &Vs[curi][0];                                                  \
    f32x16 sa0 = z16, sa1 = z16;                                                    \
    _Pragma("unroll")                                                               \
    for (int ks = 0; ks < 4; ks++) {                                                \
      const int g0 = ((ks * 2 + hi) ^ (l31 & 7)) * 8;                               \
      bf16x8 kf0 = *(const bf16x8*)&KsB[l31 * 64 + g0];                             \
      bf16x8 kf1 = *(const bf16x8*)&KsB[(32 + l31) * 64 + g0];                      \
      sa0 = __builtin_amdgcn_mfma_f32_32x32x16_bf16(kf0, qf[ks], sa0, 0, 0, 0);     \
      sa1 = __builtin_amdgcn_mfma_f32_32x32x16_bf16(kf1, qf[ks], sa1, 0, 0, 0);     \
    }                                                                               \
    SOFTMAX_BLK(sa0);                                                               \
    PVSTEP(VsB, 0, 0);                                                              \
    PVSTEP(VsB, 1, 1);                                                              \
    SOFTMAX_BLK(sa1);                                                               \
    PVSTEP(VsB, 0, 2);                                                              \
    PVSTEP(VsB, 1, 3);                                                              \
  } while (0)

  constexpr int NKB = SEQ / 64;
  STAGE(0, 0);
  for (int kb = 0; kb < NKB - 1; kb++) {
    const int cur = kb & 1;
    STAGE(kb + 1, cur ^ 1);
    WAITCNT_VM(4);
    BARRIER_FENCED();
    BODY(cur);
    BARRIER_FENCED();
  }
  WAITCNT_VM(0);
  BARRIER_FENCED();
  BODY((NKB - 1) & 1);

  float ls = ls2.x + ls2.y;
  ls += __shfl_xor(ls, 32);
  float inv = 1.0f / ls;

  u16* crow = ctx + ((size_t)(b * SEQ + qrow)) * DM + h * DK;

#define STORE_BLK(OT, DKB) do {                                                     \
    _Pragma("unroll")                                                               \
    for (int t = 0; t < 4; t++) {                                                   \
      uint2 pr;                                                                     \
      pr.x = pk2(OT[4 * t + 0] * inv, OT[4 * t + 1] * inv);                         \
      pr.y = pk2(OT[4 * t + 2] * inv, OT[4 * t + 3] * inv);                         \
      *(uint2*)&crow[(DKB) * 32 + t * 8 + hi * 4] = pr;                             \
    }                                                                               \
  } while (0)

  STORE_BLK(ot0, 0);
  STORE_BLK(ot1, 1);

#undef STAGE
#undef SOFTMAX_BLK
#undef PVSTEP
#undef BODY
#undef STORE_BLK
}

extern "C" void kernel_launch(void* const* d_in, const int* in_sizes, int n_in,
                              void* d_out, int out_size, void* d_ws, size_t ws_size,
                              hipStream_t stream)
{
  const float* q  = (const float*)d_in[0];
  const float* k  = (const float*)d_in[1];
  const float* v  = (const float*)d_in[2];
  const float* Wq = (const float*)d_in[3];
  const float* bq = (const float*)d_in[4];
  const float* Wk = (const float*)d_in[5];
  const float* bk = (const float*)d_in[6];
  const float* Wv = (const float*)d_in[7];
  const float* bv = (const float*)d_in[8];
  const float* Wo = (const float*)d_in[9];
  const float* bo = (const float*)d_in[10];

  const size_t SZ_IN  = (size_t)MTOT * DM;
  const size_t SZ_W   = (size_t)DM * DM;
  const size_t NEED_FUSED = (3 * SZ_IN + 3 * SZ_W + SZ_W + 3 * SZ_IN) * 2;  // 104 MiB

  dim3 cblk(256);
  dim3 ggq(24, 128);   // BM=64: 128 m-tiles; 3 segs x 8 n-tiles
  dim3 ggs(8, 128);    // O-proj: 1024 blocks
  dim3 agrid(BATCH * NH, SEQ / 128);

  if (ws_size >= NEED_FUSED) {
    u16* in_c  = (u16*)d_ws;
    u16* w3    = in_c + 3 * SZ_IN;
    u16* wo_c  = w3   + 3 * SZ_W;
    u16* q_ws  = wo_c + SZ_W;
    u16* k_ws  = q_ws + SZ_IN;
    u16* vt_ws = k_ws + SZ_IN;
    u16* ctx   = in_c;

    cast_all<<<14336, cblk, 0, stream>>>(q, k, v, Wq, Wk, Wv, Wo, in_c, w3, wo_c);
    gemm_k<0><<<ggq, cblk, 0, stream>>>(in_c, in_c + SZ_IN, in_c + 2 * SZ_IN, w3,
                                        bq, bk, bv, q_ws, k_ws, vt_ws, nullptr, 0);
    attn3<<<agrid, cblk, 0, stream>>>(q_ws, k_ws, vt_ws, ctx);
    gemm_k<1><<<ggs, cblk, 0, stream>>>(ctx, ctx, ctx, wo_c,
                                        bo, bo, bo, nullptr, nullptr, nullptr,
                                        (float*)d_out, 0);
  } else {
    u16* in_c  = (u16*)d_ws;
    u16* w3    = in_c + SZ_IN;
    u16* wo_c  = w3   + 3 * SZ_W;
    u16* q_ws  = wo_c + SZ_W;
    u16* k_ws  = q_ws + SZ_IN;
    u16* vt_ws = k_ws + SZ_IN;
    u16* ctx   = in_c;

    const int NA8 = MTOT * DM / 8;
    cast_w<<<2048, cblk, 0, stream>>>(Wq, Wk, Wv, Wo, w3, wo_c);
    cast_bf16<<<NA8 / 256, cblk, 0, stream>>>(q, in_c, NA8);
    gemm_k<0><<<ggs, cblk, 0, stream>>>(in_c, in_c, in_c, w3, bq, bk, bv,
                                        q_ws, k_ws, vt_ws, nullptr, 0);
    cast_bf16<<<NA8 / 256, cblk, 0, stream>>>(k, in_c, NA8);
    gemm_k<0><<<ggs, cblk, 0, stream>>>(in_c, in_c, in_c, w3, bq, bk, bv,
                                        q_ws, k_ws, vt_ws, nullptr, 1);
    cast_bf16<<<NA8 / 256, cblk, 0, stream>>>(v, in_c, NA8);
    gemm_k<0><<<ggs, cblk, 0, stream>>>(in_c, in_c, in_c, w3, bq, bk, bv,
                                        q_ws, k_ws, vt_ws, nullptr, 2);
    attn3<<<agrid, cblk, 0, stream>>>(q_ws, k_ws, vt_ws, ctx);
    gemm_k<1><<<ggs, cblk, 0, stream>>>(ctx, ctx, ctx, wo_c,
                                        bo, bo, bo, nullptr, nullptr, nullptr,
                                        (float*)d_out, 0);
  }
}

// Round 9
// 344.276 us; speedup vs baseline: 1.1065x; 1.1065x over previous
//
#include <hip/hip_runtime.h>
#include <math.h>

typedef unsigned short u16;
typedef unsigned int   u32;
typedef unsigned int   u32x2 __attribute__((ext_vector_type(2)));
typedef float f32x4  __attribute__((ext_vector_type(4)));
typedef float f32x16 __attribute__((ext_vector_type(16)));
typedef __bf16 bf16x8 __attribute__((ext_vector_type(8)));
typedef __bf16 bf16x2 __attribute__((ext_vector_type(2)));

#define SEQ   2048
#define BATCH 4
#define NH    16
#define DK    64
#define DM    1024
#define MTOT  (SEQ*BATCH)   /* 8192 rows */
#define SCL_QK 0.18033688011116016f   /* log2(e)/sqrt(64), folded into Q proj */

#if __has_builtin(__builtin_amdgcn_exp2f)
#define EXP2(x) __builtin_amdgcn_exp2f(x)
#else
#define EXP2(x) exp2f(x)
#endif

// in-place half-wave swap: d0.hi <-> d1.lo  (v_permlane32_swap_b32)
#if __has_builtin(__builtin_amdgcn_permlane32_swap)
#define PLSWAP(X, Y) do {                                          \
    u32x2 _r = __builtin_amdgcn_permlane32_swap((X), (Y), false, false); \
    (X) = _r.x; (Y) = _r.y;                                        \
  } while (0)
#else
#define PLSWAP(X, Y) \
  asm("v_permlane32_swap_b32 %0, %1" : "+v"(X), "+v"(Y))
#endif

#define WAITCNT_VM(N) asm volatile("s_waitcnt vmcnt(" #N ")" ::: "memory")
#define BARRIER_FENCED() do {                                  \
    asm volatile("" ::: "memory");                             \
    __builtin_amdgcn_s_barrier();                              \
    asm volatile("" ::: "memory");                             \
  } while (0)

static __device__ __forceinline__ u16 f2bf(float f) {
  __bf16 h = (__bf16)f;
  return __builtin_bit_cast(u16, h);
}
static __device__ __forceinline__ u32 pk2(float a, float b) {
  bf16x2 t = {(__bf16)a, (__bf16)b};          // -> v_cvt_pk_bf16_f32
  return __builtin_bit_cast(u32, t);
}

typedef __attribute__((address_space(1))) const void g1_t;
typedef __attribute__((address_space(3))) void l3_t;
static __device__ __forceinline__ void gload16(const void* g, void* l) {
  __builtin_amdgcn_global_load_lds((g1_t*)g, (l3_t*)l, 16, 0, 0);
}

static __device__ __forceinline__ void cast8(const float* __restrict__ src,
                                             u16* __restrict__ dst, int i) {
  float4 a = ((const float4*)src)[2 * i];
  float4 b = ((const float4*)src)[2 * i + 1];
  uint4 r;
  r.x = pk2(a.x, a.y); r.y = pk2(a.z, a.w);
  r.z = pk2(b.x, b.y); r.w = pk2(b.z, b.w);
  ((uint4*)dst)[i] = r;
}

// single-tensor cast (split path)
__global__ __launch_bounds__(256)
void cast_bf16(const float* __restrict__ src, u16* __restrict__ dst, int n8) {
  int i = blockIdx.x * 256 + threadIdx.x;
  if (i < n8) cast8(src, dst, i);
}

// weights-only fused cast: Wq,Wk,Wv -> w3 [3*DM,DM]; Wo -> wo_c. 2048 blocks.
__global__ __launch_bounds__(256)
void cast_w(const float* __restrict__ Wq, const float* __restrict__ Wk,
            const float* __restrict__ Wv, const float* __restrict__ Wo,
            u16* __restrict__ w3, u16* __restrict__ wo_c) {
  int bid = blockIdx.x;
  int t = bid >> 9, idx = bid & 511;
  const float* src = (t == 0) ? Wq : (t == 1) ? Wk : (t == 2) ? Wv : Wo;
  u16* dst = (t < 3) ? (w3 + (size_t)t * DM * DM) : wo_c;
  cast8(src, dst, idx * 256 + threadIdx.x);
}

// everything-cast: q,k,v (4096 blocks each) + 4 weights (512 each) = 14336 blocks.
__global__ __launch_bounds__(256)
void cast_all(const float* __restrict__ q, const float* __restrict__ k,
              const float* __restrict__ v,
              const float* __restrict__ Wq, const float* __restrict__ Wk,
              const float* __restrict__ Wv, const float* __restrict__ Wo,
              u16* __restrict__ in_c, u16* __restrict__ w3, u16* __restrict__ wo_c) {
  int bid = blockIdx.x;
  const float* src; u16* dst; int idx;
  if (bid < 12288) {
    int t = bid >> 12; idx = bid & 4095;
    src = (t == 0) ? q : (t == 1) ? k : v;
    dst = in_c + (size_t)t * MTOT * DM;
  } else {
    int wb = bid - 12288;
    int t = wb >> 9; idx = wb & 511;
    src = (t == 0) ? Wq : (t == 1) ? Wk : (t == 2) ? Wv : Wo;
    dst = (t < 3) ? (w3 + (size_t)t * DM * DM) : wo_c;
  }
  cast8(src, dst, idx * 256 + threadIdx.x);
}

// Projection GEMM — REVERTED to the twice-verified best core (R2/R4: 101 µs):
// BM=BN=128, BK=32, 256 thr / 2x2 waves, (256,4), 2-phase counted vmcnt,
// XCD-chunked swizzle. Eight rounds bracketed the design space; every
// structural alternative regressed at this shape (see session journal).
// ONE new micro-opt: seg2 (V^T) epilogue packs 4 u16 stores into one 8B store.
// Derivation: for fixed (i,j) frag, reg r=0..3 gives gm = gmb..gmb+3 with gmb
// a multiple of 4 (m0:128-mult, wm:64-mult, i*16, quad*4) -> same bb, s..s+3
// contiguous, no 2048-crossing; o2 offset (...)*SEQ + s is 4-elem (8B) aligned.
// OGEMM=0: seg = seg_base + bx>>3 picks {Q,K,V}: A in [SEQ,BATCH,DM] order, W = w3 seg,
//          epilogue: seg0 -> o0 [b,h,s,dk]*SCL_QK; seg1 -> o1 [b,h,s,dk]; seg2 -> o2 [b,h,dk,s]
// OGEMM=1: A = ctx row-major [M,DM], W = wo_c, out f32 o3 [(s*B+b)*DM+n]
template<int OGEMM>
__global__ __launch_bounds__(256, 4)
void gemm_k(const u16* __restrict__ a0, const u16* __restrict__ a1,
            const u16* __restrict__ a2, const u16* __restrict__ w3,
            const float* __restrict__ b0, const float* __restrict__ b1,
            const float* __restrict__ b2,
            u16* __restrict__ o0, u16* __restrict__ o1, u16* __restrict__ o2,
            float* __restrict__ o3, int seg_base)
{
  constexpr int BM = 128, BN = 128, BK = 32;
  __shared__ u16 As[2][BM * BK];
  __shared__ u16 Bs[2][BN * BK];

  // T1 chunked XCD swizzle (nwg % 8 == 0 -> bijective)
  const int nwg = gridDim.x * gridDim.y;
  const int bid = blockIdx.y * gridDim.x + blockIdx.x;
  const int swz = (bid & 7) * (nwg >> 3) + (bid >> 3);
  const int bx  = swz % gridDim.x;
  const int by  = swz / gridDim.x;

  const int seg = OGEMM ? 0 : (seg_base + (int)(bx >> 3));
  const int n0  = OGEMM ? bx * BN : (bx & 7) * BN;
  const int m0  = by * BM;
  const u16* A = OGEMM ? a0 : (seg == 0 ? a0 : seg == 1 ? a1 : a2);
  const u16* W = OGEMM ? w3 : (w3 + (size_t)seg * DM * DM);
  const float* bias = OGEMM ? b0 : (seg == 0 ? b0 : seg == 1 ? b1 : b2);

  const int tid  = threadIdx.x;
  const int w    = tid >> 6;
  const int lane = tid & 63;
  const int quad = lane >> 4;
  const int l15  = lane & 15;
  const int wm = (w >> 1) * 64;
  const int wn = (w & 1) * 64;

  size_t aoff[2], woff[2];
  for (int p = 0; p < 2; p++) {
    int row = w * 32 + p * 16 + (lane >> 2);
    int gm = m0 + row;
    if (OGEMM) {
      aoff[p] = (size_t)gm * DM + (lane & 3) * 8;
    } else {
      int bb = gm >> 11, s = gm & (SEQ - 1);
      aoff[p] = (size_t)(s * BATCH + bb) * DM + (lane & 3) * 8;
    }
    woff[p] = (size_t)(n0 + row) * DM + (lane & 3) * 8;
  }

  f32x4 acc[4][4];
  for (int i = 0; i < 4; i++)
    for (int j = 0; j < 4; j++)
      acc[i][j] = (f32x4){0.f, 0.f, 0.f, 0.f};

  auto stage = [&](int kt, int bufi) {
#pragma unroll
    for (int p = 0; p < 2; p++) {
      gload16(A + aoff[p] + kt * BK, &As[bufi][(w * 32 + p * 16) * BK]);
      gload16(W + woff[p] + kt * BK, &Bs[bufi][(w * 32 + p * 16) * BK]);
    }
  };
  auto compute = [&](int cur) {
    bf16x8 af[4], bfr[4];
#pragma unroll
    for (int i = 0; i < 4; i++)
      af[i] = *(const bf16x8*)&As[cur][(wm + i * 16 + l15) * BK + quad * 8];
#pragma unroll
    for (int j = 0; j < 4; j++)
      bfr[j] = *(const bf16x8*)&Bs[cur][(wn + j * 16 + l15) * BK + quad * 8];
#pragma unroll
    for (int i = 0; i < 4; i++)
#pragma unroll
      for (int j = 0; j < 4; j++)
        acc[i][j] = __builtin_amdgcn_mfma_f32_16x16x32_bf16(af[i], bfr[j], acc[i][j], 0, 0, 0);
  };

  constexpr int NKT = DM / BK;   // 32
  stage(0, 0);
  for (int kt = 0; kt < NKT - 1; kt++) {
    const int cur = kt & 1;
    stage(kt + 1, cur ^ 1);      // issue next tile first
    WAITCNT_VM(4);               // tile kt retired; kt+1's 4 loads in flight
    BARRIER_FENCED();
    compute(cur);
    BARRIER_FENCED();            // readers done before next iter's stage overwrite
  }
  WAITCNT_VM(0);                 // final tile: full drain
  BARRIER_FENCED();
  compute((NKT - 1) & 1);

  // C/D layout: col(n) = lane&15, row(m) = quad*4 + reg
  for (int j = 0; j < 4; j++) {
    int gn = n0 + wn + j * 16 + l15;
    float bv = bias[gn];
    int h = gn >> 6, dk = gn & 63;
    for (int i = 0; i < 4; i++) {
      int gmb = m0 + wm + i * 16 + quad * 4;
      if (!OGEMM && seg == 2) {
        // packed V^T store: 4 consecutive s per frag (see header derivation)
        int bb = gmb >> 11, s = gmb & (SEQ - 1);
        uint2 pr;
        pr.x = pk2(acc[i][j][0] + bv, acc[i][j][1] + bv);
        pr.y = pk2(acc[i][j][2] + bv, acc[i][j][3] + bv);
        *(uint2*)&o2[((size_t)(bb * NH + h) * DK + dk) * SEQ + s] = pr;
      } else {
        for (int r = 0; r < 4; r++) {
          int gm = gmb + r;
          float val = acc[i][j][r] + bv;
          int bb = gm >> 11, s = gm & (SEQ - 1);
          if (OGEMM) {
            o3[(size_t)(s * BATCH + bb) * DM + gn] = val;
          } else if (seg == 0) {
            o0[((size_t)(bb * NH + h) * SEQ + s) * DK + dk] = f2bf(val * SCL_QK);
          } else {
            o1[((size_t)(bb * NH + h) * SEQ + s) * DK + dk] = f2bf(val);
          }
        }
      }
    }
  }
}

// ---------------------------------------------------------------------------
// Flash attention (R7 core, kept): 32x32x16 MFMA, permlane32_swap P-exchange,
// 2-buffer depth-1 K/V pipeline with counted vmcnt.
__global__ __launch_bounds__(256, 4)
void attn3(const u16* __restrict__ Q, const u16* __restrict__ K,
           const u16* __restrict__ VT, u16* __restrict__ ctx)
{
  __shared__ u16 Ks[2][64 * 64];
  __shared__ u16 Vs[2][64 * 64];

  const int bh = blockIdx.x;
  const int qt = blockIdx.y;
  const int b  = bh >> 4, h = bh & 15;
  const int tid  = threadIdx.x;
  const int w    = tid >> 6;
  const int lane = tid & 63;
  const int l31  = lane & 31;
  const int hi   = lane >> 5;

  const u16* Qb = Q  + (size_t)bh * SEQ * DK;
  const u16* Kb = K  + (size_t)bh * SEQ * DK;
  const u16* Vb = VT + (size_t)bh * DK * SEQ;

  const int qbase = qt * 128 + w * 32;
  const int qrow  = qbase + l31;

  bf16x8 qf[4];
#pragma unroll
  for (int ks = 0; ks < 4; ks++)
    qf[ks] = *(const bf16x8*)&Qb[(size_t)qrow * DK + ks * 16 + hi * 8];

  const int r0 = tid >> 3;
  const int sw = (tid & 7) ^ (r0 & 7);

#define STAGE(kbb, bufi) do {                                                       \
    _Pragma("unroll")                                                               \
    for (int p = 0; p < 2; p++) {                                                   \
      int row = p * 32 + r0;                                                        \
      gload16(&Kb[(size_t)((kbb) * 64 + row) * DK + sw * 8],                        \
              &Ks[bufi][(p * 32 + w * 8) * 64]);                                    \
      gload16(&Vb[(size_t)row * SEQ + (kbb) * 64 + sw * 8],                         \
              &Vs[bufi][(p * 32 + w * 8) * 64]);                                    \
    }                                                                               \
  } while (0)

  f32x16 z16;
#pragma unroll
  for (int i = 0; i < 16; i++) z16[i] = 0.f;

  f32x16 ot0 = z16, ot1 = z16;
  float2 ls2 = {0.f, 0.f};

  u32 wp[8];

#define SOFTMAX_BLK(SA) do {                                                        \
    _Pragma("unroll")                                                               \
    for (int g = 0; g < 8; g++) {                                                   \
      float pa = EXP2(SA[2 * g]);                                                   \
      float pb = EXP2(SA[2 * g + 1]);                                               \
      ls2.x += pa; ls2.y += pb;                                                     \
      wp[g] = pk2(pa, pb);                                                          \
    }                                                                               \
  } while (0)

#define PVSTEP(VsB, KSB, KSL) do {                                                  \
    u32 a0 = wp[(KSB) * 4 + 0], a1 = wp[(KSB) * 4 + 1];                             \
    u32 a2 = wp[(KSB) * 4 + 2], a3 = wp[(KSB) * 4 + 3];                             \
    PLSWAP(a0, a2);                                                                 \
    PLSWAP(a1, a3);                                                                 \
    uint4 pw;                                                                       \
    pw.x = a0; pw.y = a1; pw.z = a2; pw.w = a3;                                     \
    bf16x8 pf = __builtin_bit_cast(bf16x8, pw);                                     \
    const int gg = (((KSL) * 2 + hi) ^ (l31 & 7)) * 8;                              \
    bf16x8 vf0 = *(const bf16x8*)&VsB[l31 * 64 + gg];                               \
    bf16x8 vf1 = *(const bf16x8*)&VsB[(32 + l31) * 64 + gg];                        \
    ot0 = __builtin_amdgcn_mfma_f32_32x32x16_bf16(vf0, pf, ot0, 0, 0, 0);           \
    ot1 = __builtin_amdgcn_mfma_f32_32x32x16_bf16(vf1, pf, ot1, 0, 0, 0);           \
  } while (0)

#define BODY(curi) do {                                                             \
    const u16* KsB = &Ks[curi][0];                                                  \
    const u16* VsB = &Vs[curi][0];                                                  \
    f32x16 sa0 = z16, sa1 = z16;                                                    \
    _Pragma("unroll")                                                               \
    for (int ks = 0; ks < 4; ks++) {                                                \
      const int g0 = ((ks * 2 + hi) ^ (l31 & 7)) * 8;                               \
      bf16x8 kf0 = *(const bf16x8*)&KsB[l31 * 64 + g0];                             \
      bf16x8 kf1 = *(const bf16x8*)&KsB[(32 + l31) * 64 + g0];                      \
      sa0 = __builtin_amdgcn_mfma_f32_32x32x16_bf16(kf0, qf[ks], sa0, 0, 0, 0);     \
      sa1 = __builtin_amdgcn_mfma_f32_32x32x16_bf16(kf1, qf[ks], sa1, 0, 0, 0);     \
    }                                                                               \
    SOFTMAX_BLK(sa0);                                                               \
    PVSTEP(VsB, 0, 0);                                                              \
    PVSTEP(VsB, 1, 1);                                                              \
    SOFTMAX_BLK(sa1);                                                               \
    PVSTEP(VsB, 0, 2);                                                              \
    PVSTEP(VsB, 1, 3);                                                              \
  } while (0)

  constexpr int NKB = SEQ / 64;
  STAGE(0, 0);
  for (int kb = 0; kb < NKB - 1; kb++) {
    const int cur = kb & 1;
    STAGE(kb + 1, cur ^ 1);
    WAITCNT_VM(4);
    BARRIER_FENCED();
    BODY(cur);
    BARRIER_FENCED();
  }
  WAITCNT_VM(0);
  BARRIER_FENCED();
  BODY((NKB - 1) & 1);

  float ls = ls2.x + ls2.y;
  ls += __shfl_xor(ls, 32);
  float inv = 1.0f / ls;

  u16* crow = ctx + ((size_t)(b * SEQ + qrow)) * DM + h * DK;

#define STORE_BLK(OT, DKB) do {                                                     \
    _Pragma("unroll")                                                               \
    for (int t = 0; t < 4; t++) {                                                   \
      uint2 pr;                                                                     \
      pr.x = pk2(OT[4 * t + 0] * inv, OT[4 * t + 1] * inv);                         \
      pr.y = pk2(OT[4 * t + 2] * inv, OT[4 * t + 3] * inv);                         \
      *(uint2*)&crow[(DKB) * 32 + t * 8 + hi * 4] = pr;                             \
    }                                                                               \
  } while (0)

  STORE_BLK(ot0, 0);
  STORE_BLK(ot1, 1);

#undef STAGE
#undef SOFTMAX_BLK
#undef PVSTEP
#undef BODY
#undef STORE_BLK
}

extern "C" void kernel_launch(void* const* d_in, const int* in_sizes, int n_in,
                              void* d_out, int out_size, void* d_ws, size_t ws_size,
                              hipStream_t stream)
{
  const float* q  = (const float*)d_in[0];
  const float* k  = (const float*)d_in[1];
  const float* v  = (const float*)d_in[2];
  const float* Wq = (const float*)d_in[3];
  const float* bq = (const float*)d_in[4];
  const float* Wk = (const float*)d_in[5];
  const float* bk = (const float*)d_in[6];
  const float* Wv = (const float*)d_in[7];
  const float* bv = (const float*)d_in[8];
  const float* Wo = (const float*)d_in[9];
  const float* bo = (const float*)d_in[10];

  const size_t SZ_IN  = (size_t)MTOT * DM;
  const size_t SZ_W   = (size_t)DM * DM;
  const size_t NEED_FUSED = (3 * SZ_IN + 3 * SZ_W + SZ_W + 3 * SZ_IN) * 2;  // 104 MiB

  dim3 cblk(256);
  dim3 ggq(24, 64);
  dim3 ggs(8, 64);
  dim3 agrid(BATCH * NH, SEQ / 128);

  if (ws_size >= NEED_FUSED) {
    u16* in_c  = (u16*)d_ws;
    u16* w3    = in_c + 3 * SZ_IN;
    u16* wo_c  = w3   + 3 * SZ_W;
    u16* q_ws  = wo_c + SZ_W;
    u16* k_ws  = q_ws + SZ_IN;
    u16* vt_ws = k_ws + SZ_IN;
    u16* ctx   = in_c;

    cast_all<<<14336, cblk, 0, stream>>>(q, k, v, Wq, Wk, Wv, Wo, in_c, w3, wo_c);
    gemm_k<0><<<ggq, cblk, 0, stream>>>(in_c, in_c + SZ_IN, in_c + 2 * SZ_IN, w3,
                                        bq, bk, bv, q_ws, k_ws, vt_ws, nullptr, 0);
    attn3<<<agrid, cblk, 0, stream>>>(q_ws, k_ws, vt_ws, ctx);
    gemm_k<1><<<ggs, cblk, 0, stream>>>(ctx, ctx, ctx, wo_c,
                                        bo, bo, bo, nullptr, nullptr, nullptr,
                                        (float*)d_out, 0);
  } else {
    u16* in_c  = (u16*)d_ws;
    u16* w3    = in_c + SZ_IN;
    u16* wo_c  = w3   + 3 * SZ_W;
    u16* q_ws  = wo_c + SZ_W;
    u16* k_ws  = q_ws + SZ_IN;
    u16* vt_ws = k_ws + SZ_IN;
    u16* ctx   = in_c;

    const int NA8 = MTOT * DM / 8;
    cast_w<<<2048, cblk, 0, stream>>>(Wq, Wk, Wv, Wo, w3, wo_c);
    cast_bf16<<<NA8 / 256, cblk, 0, stream>>>(q, in_c, NA8);
    gemm_k<0><<<ggs, cblk, 0, stream>>>(in_c, in_c, in_c, w3, bq, bk, bv,
                                        q_ws, k_ws, vt_ws, nullptr, 0);
    cast_bf16<<<NA8 / 256, cblk, 0, stream>>>(k, in_c, NA8);
    gemm_k<0><<<ggs, cblk, 0, stream>>>(in_c, in_c, in_c, w3, bq, bk, bv,
                                        q_ws, k_ws, vt_ws, nullptr, 1);
    cast_bf16<<<NA8 / 256, cblk, 0, stream>>>(v, in_c, NA8);
    gemm_k<0><<<ggs, cblk, 0, stream>>>(in_c, in_c, in_c, w3, bq, bk, bv,
                                        q_ws, k_ws, vt_ws, nullptr, 2);
    attn3<<<agrid, cblk, 0, stream>>>(q_ws, k_ws, vt_ws, ctx);
    gemm_k<1><<<ggs, cblk, 0, stream>>>(ctx, ctx, ctx, wo_c,
                                        bo, bo, bo, nullptr, nullptr, nullptr,
                                        (float*)d_out, 0);
  }
}

// Round 10
// 337.376 us; speedup vs baseline: 1.1292x; 1.0205x over previous
//
#include <hip/hip_runtime.h>
#include <math.h>

typedef unsigned short u16;
typedef unsigned int   u32;
typedef unsigned int   u32x2 __attribute__((ext_vector_type(2)));
typedef float f32x4  __attribute__((ext_vector_type(4)));
typedef float f32x16 __attribute__((ext_vector_type(16)));
typedef __bf16 bf16x8 __attribute__((ext_vector_type(8)));
typedef __bf16 bf16x2 __attribute__((ext_vector_type(2)));

#define SEQ   2048
#define BATCH 4
#define NH    16
#define DK    64
#define DM    1024
#define MTOT  (SEQ*BATCH)   /* 8192 rows */
#define SCL_QK 0.18033688011116016f   /* log2(e)/sqrt(64), folded into Q proj */

#if __has_builtin(__builtin_amdgcn_exp2f)
#define EXP2(x) __builtin_amdgcn_exp2f(x)
#else
#define EXP2(x) exp2f(x)
#endif

// in-place half-wave swap: d0.hi <-> d1.lo  (v_permlane32_swap_b32)
#if __has_builtin(__builtin_amdgcn_permlane32_swap)
#define PLSWAP(X, Y) do {                                          \
    u32x2 _r = __builtin_amdgcn_permlane32_swap((X), (Y), false, false); \
    (X) = _r.x; (Y) = _r.y;                                        \
  } while (0)
#else
#define PLSWAP(X, Y) \
  asm("v_permlane32_swap_b32 %0, %1" : "+v"(X), "+v"(Y))
#endif

#define WAITCNT_VM(N) asm volatile("s_waitcnt vmcnt(" #N ")" ::: "memory")
#define BARRIER_FENCED() do {                                  \
    asm volatile("" ::: "memory");                             \
    __builtin_amdgcn_s_barrier();                              \
    asm volatile("" ::: "memory");                             \
  } while (0)

static __device__ __forceinline__ u16 f2bf(float f) {
  __bf16 h = (__bf16)f;
  return __builtin_bit_cast(u16, h);
}
static __device__ __forceinline__ u32 pk2(float a, float b) {
  bf16x2 t = {(__bf16)a, (__bf16)b};          // -> v_cvt_pk_bf16_f32
  return __builtin_bit_cast(u32, t);
}

typedef __attribute__((address_space(1))) const void g1_t;
typedef __attribute__((address_space(3))) void l3_t;
static __device__ __forceinline__ void gload16(const void* g, void* l) {
  __builtin_amdgcn_global_load_lds((g1_t*)g, (l3_t*)l, 16, 0, 0);
}

static __device__ __forceinline__ void cast8(const float* __restrict__ src,
                                             u16* __restrict__ dst, int i) {
  float4 a = ((const float4*)src)[2 * i];
  float4 b = ((const float4*)src)[2 * i + 1];
  uint4 r;
  r.x = pk2(a.x, a.y); r.y = pk2(a.z, a.w);
  r.z = pk2(b.x, b.y); r.w = pk2(b.z, b.w);
  ((uint4*)dst)[i] = r;
}

// single-tensor cast (split path)
__global__ __launch_bounds__(256)
void cast_bf16(const float* __restrict__ src, u16* __restrict__ dst, int n8) {
  int i = blockIdx.x * 256 + threadIdx.x;
  if (i < n8) cast8(src, dst, i);
}

// weights-only fused cast: Wq,Wk,Wv -> w3 [3*DM,DM]; Wo -> wo_c. 2048 blocks.
__global__ __launch_bounds__(256)
void cast_w(const float* __restrict__ Wq, const float* __restrict__ Wk,
            const float* __restrict__ Wv, const float* __restrict__ Wo,
            u16* __restrict__ w3, u16* __restrict__ wo_c) {
  int bid = blockIdx.x;
  int t = bid >> 9, idx = bid & 511;
  const float* src = (t == 0) ? Wq : (t == 1) ? Wk : (t == 2) ? Wv : Wo;
  u16* dst = (t < 3) ? (w3 + (size_t)t * DM * DM) : wo_c;
  cast8(src, dst, idx * 256 + threadIdx.x);
}

// everything-cast: q,k,v (4096 blocks each) + 4 weights (512 each) = 14336 blocks.
__global__ __launch_bounds__(256)
void cast_all(const float* __restrict__ q, const float* __restrict__ k,
              const float* __restrict__ v,
              const float* __restrict__ Wq, const float* __restrict__ Wk,
              const float* __restrict__ Wv, const float* __restrict__ Wo,
              u16* __restrict__ in_c, u16* __restrict__ w3, u16* __restrict__ wo_c) {
  int bid = blockIdx.x;
  const float* src; u16* dst; int idx;
  if (bid < 12288) {
    int t = bid >> 12; idx = bid & 4095;
    src = (t == 0) ? q : (t == 1) ? k : v;
    dst = in_c + (size_t)t * MTOT * DM;
  } else {
    int wb = bid - 12288;
    int t = wb >> 9; idx = wb & 511;
    src = (t == 0) ? Wq : (t == 1) ? Wk : (t == 2) ? Wv : Wo;
    dst = (t < 3) ? (w3 + (size_t)t * DM * DM) : wo_c;
  }
  cast8(src, dst, idx * 256 + threadIdx.x);
}

// QKV projection GEMM — R9 verified core, UNCHANGED (93.5 µs):
// BM=BN=128, BK=32, 2-phase counted vmcnt, XCD swizzle, packed V^T store.
__global__ __launch_bounds__(256, 4)
void gemm_qkv(const u16* __restrict__ a0, const u16* __restrict__ a1,
              const u16* __restrict__ a2, const u16* __restrict__ w3,
              const float* __restrict__ b0, const float* __restrict__ b1,
              const float* __restrict__ b2,
              u16* __restrict__ o0, u16* __restrict__ o1, u16* __restrict__ o2,
              int seg_base)
{
  constexpr int BM = 128, BN = 128, BK = 32;
  __shared__ u16 As[2][BM * BK];
  __shared__ u16 Bs[2][BN * BK];

  const int nwg = gridDim.x * gridDim.y;
  const int bid = blockIdx.y * gridDim.x + blockIdx.x;
  const int swz = (bid & 7) * (nwg >> 3) + (bid >> 3);
  const int bx  = swz % gridDim.x;
  const int by  = swz / gridDim.x;

  const int seg = seg_base + (int)(bx >> 3);
  const int n0  = (bx & 7) * BN;
  const int m0  = by * BM;
  const u16* A = (seg == 0 ? a0 : seg == 1 ? a1 : a2);
  const u16* W = w3 + (size_t)seg * DM * DM;
  const float* bias = (seg == 0 ? b0 : seg == 1 ? b1 : b2);

  const int tid  = threadIdx.x;
  const int w    = tid >> 6;
  const int lane = tid & 63;
  const int quad = lane >> 4;
  const int l15  = lane & 15;
  const int wm = (w >> 1) * 64;
  const int wn = (w & 1) * 64;

  size_t aoff[2], woff[2];
  for (int p = 0; p < 2; p++) {
    int row = w * 32 + p * 16 + (lane >> 2);
    int gm = m0 + row;
    int bb = gm >> 11, s = gm & (SEQ - 1);
    aoff[p] = (size_t)(s * BATCH + bb) * DM + (lane & 3) * 8;
    woff[p] = (size_t)(n0 + row) * DM + (lane & 3) * 8;
  }

  f32x4 acc[4][4];
  for (int i = 0; i < 4; i++)
    for (int j = 0; j < 4; j++)
      acc[i][j] = (f32x4){0.f, 0.f, 0.f, 0.f};

  auto stage = [&](int kt, int bufi) {
#pragma unroll
    for (int p = 0; p < 2; p++) {
      gload16(A + aoff[p] + kt * BK, &As[bufi][(w * 32 + p * 16) * BK]);
      gload16(W + woff[p] + kt * BK, &Bs[bufi][(w * 32 + p * 16) * BK]);
    }
  };
  auto compute = [&](int cur) {
    bf16x8 af[4], bfr[4];
#pragma unroll
    for (int i = 0; i < 4; i++)
      af[i] = *(const bf16x8*)&As[cur][(wm + i * 16 + l15) * BK + quad * 8];
#pragma unroll
    for (int j = 0; j < 4; j++)
      bfr[j] = *(const bf16x8*)&Bs[cur][(wn + j * 16 + l15) * BK + quad * 8];
#pragma unroll
    for (int i = 0; i < 4; i++)
#pragma unroll
      for (int j = 0; j < 4; j++)
        acc[i][j] = __builtin_amdgcn_mfma_f32_16x16x32_bf16(af[i], bfr[j], acc[i][j], 0, 0, 0);
  };

  constexpr int NKT = DM / BK;   // 32
  stage(0, 0);
  for (int kt = 0; kt < NKT - 1; kt++) {
    const int cur = kt & 1;
    stage(kt + 1, cur ^ 1);
    WAITCNT_VM(4);
    BARRIER_FENCED();
    compute(cur);
    BARRIER_FENCED();
  }
  WAITCNT_VM(0);
  BARRIER_FENCED();
  compute((NKT - 1) & 1);

  for (int j = 0; j < 4; j++) {
    int gn = n0 + wn + j * 16 + l15;
    float bv = bias[gn];
    int h = gn >> 6, dk = gn & 63;
    for (int i = 0; i < 4; i++) {
      int gmb = m0 + wm + i * 16 + quad * 4;
      if (seg == 2) {
        int bb = gmb >> 11, s = gmb & (SEQ - 1);
        uint2 pr;
        pr.x = pk2(acc[i][j][0] + bv, acc[i][j][1] + bv);
        pr.y = pk2(acc[i][j][2] + bv, acc[i][j][3] + bv);
        *(uint2*)&o2[((size_t)(bb * NH + h) * DK + dk) * SEQ + s] = pr;
      } else {
        for (int r = 0; r < 4; r++) {
          int gm = gmb + r;
          float val = acc[i][j][r] + bv;
          int bb = gm >> 11, s = gm & (SEQ - 1);
          if (seg == 0) {
            o0[((size_t)(bb * NH + h) * SEQ + s) * DK + dk] = f2bf(val * SCL_QK);
          } else {
            o1[((size_t)(bb * NH + h) * SEQ + s) * DK + dk] = f2bf(val);
          }
        }
      }
    }
  }
}

// O-projection GEMM — v10: BM=128 x BN=64 x BK=32. Grid (16,64) = 1024 blocks
// -> 4 blocks/CU in ONE exact round (vs 512 @ 2/CU before: only 8 waves/CU in
// a latency-bound loop). LDS 24 KB; (256,6) caps VGPR at 85 >> ~40 needed
// (R8 measured this acc size at 40 VGPR -> no R7-style spill). Fetch bounded:
// W = 2 MB (L2-resident/XCD); A panel shared by all 16 n-blocks inside the
// XCD chunk (128 blocks = 8 m-rows). Same 2-phase counted-vmcnt schedule;
// stage = 2 A-gloads + 1 B-gload -> vmcnt(3).
__global__ __launch_bounds__(256, 6)
void gemm_o(const u16* __restrict__ ctx, const u16* __restrict__ wo_c,
            const float* __restrict__ bo, float* __restrict__ out)
{
  constexpr int BM = 128, BN = 64, BK = 32;
  __shared__ u16 As[2][BM * BK];   // 16 KB
  __shared__ u16 Bs[2][BN * BK];   //  8 KB

  const int nwg = gridDim.x * gridDim.y;   // 1024, %8==0
  const int bid = blockIdx.y * gridDim.x + blockIdx.x;
  const int swz = (bid & 7) * (nwg >> 3) + (bid >> 3);
  const int bx  = swz % gridDim.x;
  const int by  = swz / gridDim.x;

  const int n0  = bx * BN;
  const int m0  = by * BM;

  const int tid  = threadIdx.x;
  const int w    = tid >> 6;
  const int lane = tid & 63;
  const int quad = lane >> 4;
  const int l15  = lane & 15;
  const int wm = (w >> 1) * 64;
  const int wn = (w & 1) * 32;

  size_t aoff[2], woff;
  for (int p = 0; p < 2; p++) {
    int row = w * 32 + p * 16 + (lane >> 2);
    aoff[p] = (size_t)(m0 + row) * DM + (lane & 3) * 8;
  }
  woff = (size_t)(n0 + w * 16 + (lane >> 2)) * DM + (lane & 3) * 8;

  f32x4 acc[4][2];
  for (int i = 0; i < 4; i++)
    for (int j = 0; j < 2; j++)
      acc[i][j] = (f32x4){0.f, 0.f, 0.f, 0.f};

  auto stage = [&](int kt, int bufi) {
#pragma unroll
    for (int p = 0; p < 2; p++)
      gload16(ctx + aoff[p] + kt * BK, &As[bufi][(w * 32 + p * 16) * BK]);
    gload16(wo_c + woff + kt * BK, &Bs[bufi][w * 16 * BK]);
  };
  auto compute = [&](int cur) {
    bf16x8 af[4], bfr[2];
#pragma unroll
    for (int i = 0; i < 4; i++)
      af[i] = *(const bf16x8*)&As[cur][(wm + i * 16 + l15) * BK + quad * 8];
#pragma unroll
    for (int j = 0; j < 2; j++)
      bfr[j] = *(const bf16x8*)&Bs[cur][(wn + j * 16 + l15) * BK + quad * 8];
#pragma unroll
    for (int i = 0; i < 4; i++)
#pragma unroll
      for (int j = 0; j < 2; j++)
        acc[i][j] = __builtin_amdgcn_mfma_f32_16x16x32_bf16(af[i], bfr[j], acc[i][j], 0, 0, 0);
  };

  constexpr int NKT = DM / BK;   // 32
  stage(0, 0);
  for (int kt = 0; kt < NKT - 1; kt++) {
    const int cur = kt & 1;
    stage(kt + 1, cur ^ 1);      // issue next tile first (3 loads)
    WAITCNT_VM(3);               // tile kt retired; kt+1's 3 loads in flight
    BARRIER_FENCED();
    compute(cur);
    BARRIER_FENCED();
  }
  WAITCNT_VM(0);
  BARRIER_FENCED();
  compute((NKT - 1) & 1);

  // C/D layout: col(n) = lane&15, row(m) = quad*4 + reg
  for (int j = 0; j < 2; j++) {
    int gn = n0 + wn + j * 16 + l15;
    float bv = bo[gn];
    for (int i = 0; i < 4; i++) {
      int gmb = m0 + wm + i * 16 + quad * 4;
      for (int r = 0; r < 4; r++) {
        int gm = gmb + r;
        int bb = gm >> 11, s = gm & (SEQ - 1);
        out[(size_t)(s * BATCH + bb) * DM + gn] = acc[i][j][r] + bv;
      }
    }
  }
}

// ---------------------------------------------------------------------------
// Flash attention (R7/R9 core, unchanged): 32x32x16 MFMA, permlane32_swap
// P-exchange, 2-buffer depth-1 K/V pipeline with counted vmcnt.
__global__ __launch_bounds__(256, 4)
void attn3(const u16* __restrict__ Q, const u16* __restrict__ K,
           const u16* __restrict__ VT, u16* __restrict__ ctx)
{
  __shared__ u16 Ks[2][64 * 64];
  __shared__ u16 Vs[2][64 * 64];

  const int bh = blockIdx.x;
  const int qt = blockIdx.y;
  const int b  = bh >> 4, h = bh & 15;
  const int tid  = threadIdx.x;
  const int w    = tid >> 6;
  const int lane = tid & 63;
  const int l31  = lane & 31;
  const int hi   = lane >> 5;

  const u16* Qb = Q  + (size_t)bh * SEQ * DK;
  const u16* Kb = K  + (size_t)bh * SEQ * DK;
  const u16* Vb = VT + (size_t)bh * DK * SEQ;

  const int qbase = qt * 128 + w * 32;
  const int qrow  = qbase + l31;

  bf16x8 qf[4];
#pragma unroll
  for (int ks = 0; ks < 4; ks++)
    qf[ks] = *(const bf16x8*)&Qb[(size_t)qrow * DK + ks * 16 + hi * 8];

  const int r0 = tid >> 3;
  const int sw = (tid & 7) ^ (r0 & 7);

#define STAGE(kbb, bufi) do {                                                       \
    _Pragma("unroll")                                                               \
    for (int p = 0; p < 2; p++) {                                                   \
      int row = p * 32 + r0;                                                        \
      gload16(&Kb[(size_t)((kbb) * 64 + row) * DK + sw * 8],                        \
              &Ks[bufi][(p * 32 + w * 8) * 64]);                                    \
      gload16(&Vb[(size_t)row * SEQ + (kbb) * 64 + sw * 8],                         \
              &Vs[bufi][(p * 32 + w * 8) * 64]);                                    \
    }                                                                               \
  } while (0)

  f32x16 z16;
#pragma unroll
  for (int i = 0; i < 16; i++) z16[i] = 0.f;

  f32x16 ot0 = z16, ot1 = z16;
  float2 ls2 = {0.f, 0.f};

  u32 wp[8];

#define SOFTMAX_BLK(SA) do {                                                        \
    _Pragma("unroll")                                                               \
    for (int g = 0; g < 8; g++) {                                                   \
      float pa = EXP2(SA[2 * g]);                                                   \
      float pb = EXP2(SA[2 * g + 1]);                                               \
      ls2.x += pa; ls2.y += pb;                                                     \
      wp[g] = pk2(pa, pb);                                                          \
    }                                                                               \
  } while (0)

#define PVSTEP(VsB, KSB, KSL) do {                                                  \
    u32 a0 = wp[(KSB) * 4 + 0], a1 = wp[(KSB) * 4 + 1];                             \
    u32 a2 = wp[(KSB) * 4 + 2], a3 = wp[(KSB) * 4 + 3];                             \
    PLSWAP(a0, a2);                                                                 \
    PLSWAP(a1, a3);                                                                 \
    uint4 pw;                                                                       \
    pw.x = a0; pw.y = a1; pw.z = a2; pw.w = a3;                                     \
    bf16x8 pf = __builtin_bit_cast(bf16x8, pw);                                     \
    const int gg = (((KSL) * 2 + hi) ^ (l31 & 7)) * 8;                              \
    bf16x8 vf0 = *(const bf16x8*)&VsB[l31 * 64 + gg];                               \
    bf16x8 vf1 = *(const bf16x8*)&VsB[(32 + l31) * 64 + gg];                        \
    ot0 = __builtin_amdgcn_mfma_f32_32x32x16_bf16(vf0, pf, ot0, 0, 0, 0);           \
    ot1 = __builtin_amdgcn_mfma_f32_32x32x16_bf16(vf1, pf, ot1, 0, 0, 0);           \
  } while (0)

#define BODY(curi) do {                                                             \
    const u16* KsB = &Ks[curi][0];                                                  \
    const u16* VsB = &Vs[curi][0];                                                  \
    f32x16 sa0 = z16, sa1 = z16;                                                    \
    _Pragma("unroll")                                                               \
    for (int ks = 0; ks < 4; ks++) {                                                \
      const int g0 = ((ks * 2 + hi) ^ (l31 & 7)) * 8;                               \
      bf16x8 kf0 = *(const bf16x8*)&KsB[l31 * 64 + g0];                             \
      bf16x8 kf1 = *(const bf16x8*)&KsB[(32 + l31) * 64 + g0];                      \
      sa0 = __builtin_amdgcn_mfma_f32_32x32x16_bf16(kf0, qf[ks], sa0, 0, 0, 0);     \
      sa1 = __builtin_amdgcn_mfma_f32_32x32x16_bf16(kf1, qf[ks], sa1, 0, 0, 0);     \
    }                                                                               \
    SOFTMAX_BLK(sa0);                                                               \
    PVSTEP(VsB, 0, 0);                                                              \
    PVSTEP(VsB, 1, 1);                                                              \
    SOFTMAX_BLK(sa1);                                                               \
    PVSTEP(VsB, 0, 2);                                                              \
    PVSTEP(VsB, 1, 3);                                                              \
  } while (0)

  constexpr int NKB = SEQ / 64;
  STAGE(0, 0);
  for (int kb = 0; kb < NKB - 1; kb++) {
    const int cur = kb & 1;
    STAGE(kb + 1, cur ^ 1);
    WAITCNT_VM(4);
    BARRIER_FENCED();
    BODY(cur);
    BARRIER_FENCED();
  }
  WAITCNT_VM(0);
  BARRIER_FENCED();
  BODY((NKB - 1) & 1);

  float ls = ls2.x + ls2.y;
  ls += __shfl_xor(ls, 32);
  float inv = 1.0f / ls;

  u16* crow = ctx + ((size_t)(b * SEQ + qrow)) * DM + h * DK;

#define STORE_BLK(OT, DKB) do {                                                     \
    _Pragma("unroll")                                                               \
    for (int t = 0; t < 4; t++) {                                                   \
      uint2 pr;                                                                     \
      pr.x = pk2(OT[4 * t + 0] * inv, OT[4 * t + 1] * inv);                         \
      pr.y = pk2(OT[4 * t + 2] * inv, OT[4 * t + 3] * inv);                         \
      *(uint2*)&crow[(DKB) * 32 + t * 8 + hi * 4] = pr;                             \
    }                                                                               \
  } while (0)

  STORE_BLK(ot0, 0);
  STORE_BLK(ot1, 1);

#undef STAGE
#undef SOFTMAX_BLK
#undef PVSTEP
#undef BODY
#undef STORE_BLK
}

extern "C" void kernel_launch(void* const* d_in, const int* in_sizes, int n_in,
                              void* d_out, int out_size, void* d_ws, size_t ws_size,
                              hipStream_t stream)
{
  const float* q  = (const float*)d_in[0];
  const float* k  = (const float*)d_in[1];
  const float* v  = (const float*)d_in[2];
  const float* Wq = (const float*)d_in[3];
  const float* bq = (const float*)d_in[4];
  const float* Wk = (const float*)d_in[5];
  const float* bk = (const float*)d_in[6];
  const float* Wv = (const float*)d_in[7];
  const float* bv = (const float*)d_in[8];
  const float* Wo = (const float*)d_in[9];
  const float* bo = (const float*)d_in[10];

  const size_t SZ_IN  = (size_t)MTOT * DM;
  const size_t SZ_W   = (size_t)DM * DM;
  const size_t NEED_FUSED = (3 * SZ_IN + 3 * SZ_W + SZ_W + 3 * SZ_IN) * 2;  // 104 MiB

  dim3 cblk(256);
  dim3 ggq(24, 64);
  dim3 ggo(16, 64);    // O-proj: BN=64 -> 16 n-tiles, 1024 blocks, 4/CU
  dim3 agrid(BATCH * NH, SEQ / 128);

  if (ws_size >= NEED_FUSED) {
    u16* in_c  = (u16*)d_ws;
    u16* w3    = in_c + 3 * SZ_IN;
    u16* wo_c  = w3   + 3 * SZ_W;
    u16* q_ws  = wo_c + SZ_W;
    u16* k_ws  = q_ws + SZ_IN;
    u16* vt_ws = k_ws + SZ_IN;
    u16* ctx   = in_c;

    cast_all<<<14336, cblk, 0, stream>>>(q, k, v, Wq, Wk, Wv, Wo, in_c, w3, wo_c);
    gemm_qkv<<<ggq, cblk, 0, stream>>>(in_c, in_c + SZ_IN, in_c + 2 * SZ_IN, w3,
                                       bq, bk, bv, q_ws, k_ws, vt_ws, 0);
    attn3<<<agrid, cblk, 0, stream>>>(q_ws, k_ws, vt_ws, ctx);
    gemm_o<<<ggo, cblk, 0, stream>>>(ctx, wo_c, bo, (float*)d_out);
  } else {
    u16* in_c  = (u16*)d_ws;
    u16* w3    = in_c + SZ_IN;
    u16* wo_c  = w3   + 3 * SZ_W;
    u16* q_ws  = wo_c + SZ_W;
    u16* k_ws  = q_ws + SZ_IN;
    u16* vt_ws = k_ws + SZ_IN;
    u16* ctx   = in_c;

    const int NA8 = MTOT * DM / 8;
    dim3 ggq1(8, 64);
    cast_w<<<2048, cblk, 0, stream>>>(Wq, Wk, Wv, Wo, w3, wo_c);
    cast_bf16<<<NA8 / 256, cblk, 0, stream>>>(q, in_c, NA8);
    gemm_qkv<<<ggq1, cblk, 0, stream>>>(in_c, in_c, in_c, w3, bq, bk, bv,
                                        q_ws, k_ws, vt_ws, 0);
    cast_bf16<<<NA8 / 256, cblk, 0, stream>>>(k, in_c, NA8);
    gemm_qkv<<<ggq1, cblk, 0, stream>>>(in_c, in_c, in_c, w3, bq, bk, bv,
                                        q_ws, k_ws, vt_ws, 1);
    cast_bf16<<<NA8 / 256, cblk, 0, stream>>>(v, in_c, NA8);
    gemm_qkv<<<ggq1, cblk, 0, stream>>>(in_c, in_c, in_c, w3, bq, bk, bv,
                                        q_ws, k_ws, vt_ws, 2);
    attn3<<<agrid, cblk, 0, stream>>>(q_ws, k_ws, vt_ws, ctx);
    gemm_o<<<ggo, cblk, 0, stream>>>(ctx, wo_c, bo, (float*)d_out);
  }
}